// Round 12
// baseline (65.233 us; speedup 1.0000x reference)
//
#include <hip/hip_runtime.h>

#define N_SAMPLES   8192
#define CODE_LEN    128
#define NUM_CLASSES 1000
#define PAD_CLASSES 1024    // padded with duplicates of classes 0..23
#define MAINBLK     512     // 16 samples/block, 4/wave

// ws layout:
//   [0, 2048)       float    bce_part[512]
//   [4096, 6144)    unsigned sig_part[512]
//   [16384, 32768)  uint4    cw_packed[1024]  (padded; duplicates can't
//                                              change a min)
//
// Bit layout: lane l handles elements 2l, 2l+1 (float2 loads). uint4 =
// (even_lo, even_hi, odd_lo, odd_hi). XOR+popcount is permutation-
// invariant, so any fixed order works as long as pred and table agree.
//
// R12 changes (structure fixed at 3 nodes, no atomics):
//  - main stages the 16-KB packed table in LDS once per block (4 coalesced
//    uint4 loads/thread); sigma reads ds_read_b128 (~20 cy) instead of L2
//    (~200 cy) — matters at 2 waves/SIMD occupancy. Table L2 traffic 32->8 MB.
//  - BCE scalar chains hoisted: all 4 target loads, then all 4 cw_packed
//    quads, then vector loads + logs (chains overlap instead of serializing).
__global__ __launch_bounds__(256) void pack_kernel(
        const float* __restrict__ codewords, uint4* __restrict__ cw_packed) {
    const int w = threadIdx.x >> 6, l = threadIdx.x & 63;
    const int c = blockIdx.x * 4 + w;            // 0..1023
    const int src = (c < NUM_CLASSES) ? c : (c - NUM_CLASSES);
    const float2 v = ((const float2*)(codewords + src * CODE_LEN))[l];
    unsigned long long be = __ballot(v.x > 0.5f);   // even elements
    unsigned long long bo = __ballot(v.y > 0.5f);   // odd elements
    if (l == 0)
        cw_packed[c] = make_uint4((unsigned)be, (unsigned)(be >> 32),
                                  (unsigned)bo, (unsigned)(bo >> 32));
}

__global__ __launch_bounds__(256) void main_kernel(
        const float* __restrict__ output, const int* __restrict__ target,
        const uint4* __restrict__ cw_packed,
        float* __restrict__ bce_part, unsigned* __restrict__ sig_part) {
    __shared__ __align__(16) uint4 lcw[PAD_CLASSES];   // 16 KB
    __shared__ float    wbce[4];
    __shared__ unsigned wsig[4];
    const int tid = threadIdx.x;
    const int w   = tid >> 6;               // wave 0..3
    const int l   = tid & 63;
    const int b   = blockIdx.x;

    // --- stage table: 4 coalesced uint4 loads per thread ---
    #pragma unroll
    for (int k = 0; k < 4; ++k)
        lcw[tid + 256 * k] = cw_packed[tid + 256 * k];

    // --- BCE + pred pack: wave w owns samples 4w..4w+3; chains hoisted ---
    int   t4[4];
    uint4 q4[4];
    #pragma unroll
    for (int j = 0; j < 4; ++j)
        t4[j] = __builtin_amdgcn_readfirstlane(target[b * 16 + w * 4 + j]);
    #pragma unroll
    for (int j = 0; j < 4; ++j)
        q4[j] = cw_packed[t4[j]];           // wave-uniform -> s_load 16B

    float bce = 0.f;
    uint4 pred[4];
    #pragma unroll
    for (int j = 0; j < 4; ++j) {
        const int i = b * 16 + w * 4 + j;
        const float2 o = ((const float2*)(output + i * CODE_LEN))[l];
        unsigned ce = ((l < 32) ? q4[j].x : q4[j].y) >> (l & 31);
        unsigned co = ((l < 32) ? q4[j].z : q4[j].w) >> (l & 31);
        float a0 = (ce & 1u) ? o.x : 1.0f - o.x;   // -log(cw ? o : 1-o)
        float a1 = (co & 1u) ? o.y : 1.0f - o.y;
        bce -= __logf(a0) + __logf(a1);
        unsigned long long pe = __ballot(o.x > 0.5f);
        unsigned long long po = __ballot(o.y > 0.5f);
        pred[j] = make_uint4((unsigned)pe, (unsigned)(pe >> 32),
                             (unsigned)po, (unsigned)(po >> 32));
    }
    #pragma unroll
    for (int m = 1; m <= 32; m <<= 1) bce += __shfl_xor(bce, m);
    if (l == 0) wbce[w] = bce;
    __syncthreads();                        // table staged

    // --- sigma: 16 unrolled ds_read_b128 iterations over LDS table ---
    unsigned best[4] = {0xFFFFFFFFu, 0xFFFFFFFFu, 0xFFFFFFFFu, 0xFFFFFFFFu};
    #pragma unroll
    for (int k = 0; k < 16; ++k) {
        uint4 cw = lcw[l + 64 * k];
        #pragma unroll
        for (int j = 0; j < 4; ++j) {
            unsigned d = __popc(pred[j].x ^ cw.x) + __popc(pred[j].y ^ cw.y)
                       + __popc(pred[j].z ^ cw.z) + __popc(pred[j].w ^ cw.w);
            best[j] = min(best[j], d);
        }
    }
    #pragma unroll
    for (int m = 1; m <= 32; m <<= 1) {
        #pragma unroll
        for (int j = 0; j < 4; ++j)
            best[j] = min(best[j], (unsigned)__shfl_xor((int)best[j], m));
    }
    if (l == 0) wsig[w] = best[0] + best[1] + best[2] + best[3];
    __syncthreads();

    // --- epilogue: plain per-block partial stores, NO atomics ---
    if (tid == 0) {
        bce_part[b] = wbce[0] + wbce[1] + wbce[2] + wbce[3];
        sig_part[b] = wsig[0] + wsig[1] + wsig[2] + wsig[3];
    }
}

__global__ __launch_bounds__(512) void finalize_kernel(
        const float* __restrict__ bce_part, const unsigned* __restrict__ sig_part,
        float* __restrict__ out) {
    __shared__ float    fb8[8];
    __shared__ unsigned fs8[8];
    const int tid = threadIdx.x;
    const int w   = tid >> 6, l = tid & 63;
    float    fb = bce_part[tid];
    unsigned fs = sig_part[tid];
    #pragma unroll
    for (int m = 1; m <= 32; m <<= 1) {
        fb += __shfl_xor(fb, m);
        fs += (unsigned)__shfl_xor((int)fs, m);
    }
    if (l == 0) { fb8[w] = fb; fs8[w] = fs; }
    __syncthreads();
    if (tid == 0) {
        float    tb = 0.f;
        unsigned ts = 0u;
        #pragma unroll
        for (int k = 0; k < 8; ++k) { tb += fb8[k]; ts += fs8[k]; }
        out[0] = tb / (float)(N_SAMPLES * CODE_LEN) + (float)ts / (float)N_SAMPLES;
    }
}

extern "C" void kernel_launch(void* const* d_in, const int* in_sizes, int n_in,
                              void* d_out, int out_size, void* d_ws, size_t ws_size,
                              hipStream_t stream) {
    const float* output    = (const float*)d_in[0];   // [8192,128] f32
    const float* codewords = (const float*)d_in[1];   // [1000,128] f32
    const int*   target    = (const int*)d_in[2];     // [8192] int32
    float*       out       = (float*)d_out;

    float*    bce_part  = (float*)d_ws;
    unsigned* sig_part  = (unsigned*)((char*)d_ws + 4096);
    uint4*    cw_packed = (uint4*)((char*)d_ws + 16384);

    pack_kernel<<<PAD_CLASSES / 4, 256, 0, stream>>>(codewords, cw_packed);
    main_kernel<<<MAINBLK, 256, 0, stream>>>(
        output, target, cw_packed, bce_part, sig_part);
    finalize_kernel<<<1, 512, 0, stream>>>(bce_part, sig_part, out);
}